// Round 4
// baseline (31.529 us; speedup 1.0000x reference)
//
#include <hip/hip_runtime.h>
#include <math.h>

#define N_BUS 127
#define BATCH 4096
#define NUM_CS 200
#define STATE_DIM 858   // 4 + 2*127 + 3*200
#define EV_START 258    // 4 + 2*127
#define COLS 8          // batch columns per block -> 512 blocks, 2 blocks/CU
#define NITER 10        // fixed count: reference freezes at ~7 (contraction ~0.015)
#define KPAD 136        // lcb row stride in bf16 units

typedef __attribute__((ext_vector_type(8))) short short8;
typedef __attribute__((ext_vector_type(4))) short short4v;
typedef __attribute__((ext_vector_type(4))) float f32x4;

// RNE float -> bf16 (no NaN handling needed for this data)
static __device__ __forceinline__ short f2bf(float f) {
    unsigned u = __float_as_uint(f);
    return (short)((u + 0x7FFFu + ((u >> 16) & 1u)) >> 16);
}

// Build per-wave MFMA A-fragments of K in bf16 (layout verified in round 3).
// frag index: (((w*2 + t)*4 + kt)*2 + p)*64 + lane ; element i of lane l:
//   row = 32w + 16t + (l&15), k = 32kt + 8*(l>>4) + i ; p=0 -> Re(K), p=1 -> Im(K)
__global__ __launch_bounds__(256) void prep_frags(const float2* __restrict__ K,
                                                  short8* __restrict__ frags) {
    int idx = blockIdx.x * 256 + threadIdx.x;   // 0..4095
    int l    = idx & 63;
    int rest = idx >> 6;
    int p  = rest & 1;
    int kt = (rest >> 1) & 3;
    int t  = (rest >> 3) & 1;
    int w  = rest >> 4;
    int row = 32 * w + 16 * t + (l & 15);
    int k0  = 32 * kt + 8 * (l >> 4);
    short8 o;
    #pragma unroll
    for (int i = 0; i < 8; ++i) {
        float val = 0.0f;
        int k = k0 + i;
        if (row < N_BUS && k < N_BUS) {
            float2 e = K[row * N_BUS + k];
            val = p ? e.y : e.x;
        }
        o[i] = f2bf(val);
    }
    frags[idx] = o;
}

__global__ __launch_bounds__(256, 2) void vvl_main(const float* __restrict__ action,
                                                   const float* __restrict__ state,
                                                   const short8* __restrict__ frags,
                                                   const float2* __restrict__ Lp,
                                                   float* __restrict__ out) {
    __shared__ float  ev[COLS][128];
    __shared__ float2 evseg[COLS][300];                     // staged EV segment
    __shared__ __align__(16) short lcb[2][2][16][KPAD];     // [buf][part][col][k]
    __shared__ float lossred[16];

    const int tid = threadIdx.x;
    const int w  = tid >> 6;         // wave 0..3 -> rows [32w, 32w+32)
    const int l  = tid & 63;
    const int cc = l & 15;           // lcb column slot (8..15 duplicate 0..7)
    const int c8 = cc & 7;           // real batch column within tile
    const int g  = l >> 4;           // lane group 0..3
    const int b0 = blockIdx.x * COLS;

    // --- load K A-fragments into registers (held for the whole kernel) ---
    short8 AKr[2][4], AKi[2][4];
    #pragma unroll
    for (int t = 0; t < 2; ++t)
        #pragma unroll
        for (int kt = 0; kt < 4; ++kt) {
            AKr[t][kt] = frags[(((w * 2 + t) * 4 + kt) * 2 + 0) * 64 + l];
            AKi[t][kt] = frags[(((w * 2 + t) * 4 + kt) * 2 + 1) * 64 + l];
        }

    // zero ev + loss accumulators; stage EV segment (coalesced float2)
    for (int i = tid; i < COLS * 128; i += 256) (&ev[0][0])[i] = 0.0f;
    if (tid < 16) lossred[tid] = 0.0f;
    {
        int col = tid >> 5, j = tid & 31;
        const float2* st2 = (const float2*)(state + (size_t)(b0 + col) * STATE_DIM);
        #pragma unroll
        for (int jj = 0; jj < 10; ++jj) {
            int idx = j + 32 * jj;
            if (idx < 300) evseg[col][idx] = st2[129 + idx];   // floats 258..857
        }
    }
    __syncthreads();

    // --- EV power + scatter-add to buses: 32 threads per column ---
    {
        int col = tid >> 5, j = tid & 31;
        const float* act_row = action + (size_t)(b0 + col) * NUM_CS;
        const float* seg = (const float*)&evseg[col][0];
        for (int cs = j; cs < NUM_CS; cs += 32) {
            float a    = act_row[cs];
            float cap  = seg[3 * cs];
            float busf = seg[3 * cs + 2];
            float conn = (cap > 0.0f) ? 1.0f : 0.0f;
            float mch  = fminf(22.0f,  conn * (70.0f - cap) * 4.0f);  // /0.25 == *4
            float mds  = fmaxf(-22.0f, conn * (15.0f - cap) * 4.0f);
            float pw   = fmaxf(fminf(a * 22.17f, mch), mds);
            int bi = (int)busf;
            bi = bi < 0 ? 0 : (bi > N_BUS - 1 ? N_BUS - 1 : bi);
            atomicAdd(&ev[col][bi], pw);
        }
    }
    __syncthreads();

    // --- per-lane state: 8 rows (2 M-tiles x 4 regs) of column c8 ---
    // Row ownership matches the MFMA C/D layout: row = 32w + 16t + 4g + r.
    const float* st_row = state + (size_t)(b0 + c8) * STATE_DIM;
    float Sr[8], Si[8], lmr[8], lmi[8], vr[8], vi[8];
    #pragma unroll
    for (int t = 0; t < 2; ++t)
        #pragma unroll
        for (int r = 0; r < 4; ++r) {
            int idx = t * 4 + r;
            int row = 32 * w + 16 * t + 4 * g + r;
            if (row < N_BUS) {
                Sr[idx] = (st_row[4 + row] + ev[c8][row]) * 1e-3f;
                Si[idx] = st_row[4 + N_BUS + row] * 1e-3f;
                float2 lp = Lp[row];
                lmr[idx] = lp.x; lmi[idx] = lp.y;
            } else {  // pad row 127: S=0 -> Lc=0; A-col 127 is zero anyway
                Sr[idx] = 0.0f; Si[idx] = 0.0f; lmr[idx] = 1.0f; lmi[idx] = 0.0f;
            }
            vr[idx] = 1.0f; vi[idx] = 0.0f;
        }

    // --- fixed-point loop: v = K @ conj(S/v) + L on matrix cores ---
    for (int it = 0; it < NITER; ++it) {
        const int buf = it & 1;
        // Lc = conj(S)*v/|v|^2 in fp32, round to bf16, write [part][col][k=row]
        #pragma unroll
        for (int t = 0; t < 2; ++t) {
            short4v pr, pi;
            #pragma unroll
            for (int r = 0; r < 4; ++r) {
                int idx = t * 4 + r;
                float d   = vr[idx] * vr[idx] + vi[idx] * vi[idx];
                float inv = __builtin_amdgcn_rcpf(d);
                pr[r] = f2bf((Sr[idx] * vr[idx] + Si[idx] * vi[idx]) * inv);
                pi[r] = f2bf((Sr[idx] * vi[idx] - Si[idx] * vr[idx]) * inv);
            }
            int k0 = 32 * w + 16 * t + 4 * g;
            *(short4v*)&lcb[buf][0][cc][k0] = pr;
            *(short4v*)&lcb[buf][1][cc][k0] = pi;
        }
        __syncthreads();   // writes visible; WAR handled by double buffer

        // B fragments: lane l -> col l&15, k = 32kt + 8g + i  (16B contiguous)
        short8 Br[4], Bi8[4], Bin[4];
        #pragma unroll
        for (int kt = 0; kt < 4; ++kt) {
            Br[kt]  = *(const short8*)&lcb[buf][0][cc][32 * kt + 8 * g];
            Bi8[kt] = *(const short8*)&lcb[buf][1][cc][32 * kt + 8 * g];
        }
        #pragma unroll
        for (int kt = 0; kt < 4; ++kt)
            #pragma unroll
            for (int i = 0; i < 8; ++i)
                Bin[kt][i] = Bi8[kt][i] ^ (short)0x8000;   // -Li

        // Cre = Kr@Lr + Ki@(-Li) ; Cim = Kr@Li + Ki@Lr   (fp32 accum)
        #pragma unroll
        for (int t = 0; t < 2; ++t) {
            f32x4 are = {0.f, 0.f, 0.f, 0.f}, aim = {0.f, 0.f, 0.f, 0.f};
            #pragma unroll
            for (int kt = 0; kt < 4; ++kt) {
                are = __builtin_amdgcn_mfma_f32_16x16x32_bf16(AKr[t][kt], Br[kt],  are, 0, 0, 0);
                are = __builtin_amdgcn_mfma_f32_16x16x32_bf16(AKi[t][kt], Bin[kt], are, 0, 0, 0);
                aim = __builtin_amdgcn_mfma_f32_16x16x32_bf16(AKr[t][kt], Bi8[kt], aim, 0, 0, 0);
                aim = __builtin_amdgcn_mfma_f32_16x16x32_bf16(AKi[t][kt], Br[kt],  aim, 0, 0, 0);
            }
            // D layout: col = lane&15 (=cc), row = 32w + 16t + 4g + r -> matches v
            #pragma unroll
            for (int r = 0; r < 4; ++r) {
                vr[t * 4 + r] = are[r] + lmr[t * 4 + r];
                vi[t * 4 + r] = aim[r] + lmi[t * 4 + r];
            }
        }
    }

    // --- loss = 1000 * sum_n min(0, 0.05 - |1 - |v||) per column ---
    float ls = 0.0f;
    #pragma unroll
    for (int t = 0; t < 2; ++t)
        #pragma unroll
        for (int r = 0; r < 4; ++r) {
            int row = 32 * w + 16 * t + 4 * g + r;
            if (row < N_BUS) {
                int idx = t * 4 + r;
                float na = sqrtf(vr[idx] * vr[idx] + vi[idx] * vi[idx]);
                ls += fminf(0.0f, 0.05f - fabsf(1.0f - na));
            }
        }
    // sum the 4 lane-groups sharing column cc within the wave
    ls += __shfl_xor(ls, 16);
    ls += __shfl_xor(ls, 32);
    if (g == 0) atomicAdd(&lossred[cc], ls);   // 4 waves -> block total
    __syncthreads();
    if (tid < COLS) out[b0 + tid] = 1000.0f * lossred[tid];
}

extern "C" void kernel_launch(void* const* d_in, const int* in_sizes, int n_in,
                              void* d_out, int out_size, void* d_ws, size_t ws_size,
                              hipStream_t stream) {
    const float*  action = (const float*)d_in[0];
    const float*  state  = (const float*)d_in[1];
    const float2* K      = (const float2*)d_in[2];
    const float2* Lp     = (const float2*)d_in[3];
    float*  out   = (float*)d_out;
    short8* frags = (short8*)d_ws;   // 4096 frags * 16 B = 64 KiB

    prep_frags<<<16, 256, 0, stream>>>(K, frags);
    vvl_main<<<BATCH / COLS, 256, 0, stream>>>(action, state, frags, Lp, out);
}

// Round 5
// 18.405 us; speedup vs baseline: 1.7130x; 1.7130x over previous
//
#include <hip/hip_runtime.h>
#include <math.h>

#define N_BUS 127
#define BATCH 4096
#define NUM_CS 200
#define STATE_DIM 858   // 4 + 2*127 + 3*200
#define EV_START 258    // 4 + 2*127
#define COLS 16         // batch columns per block -> 256 blocks of 512 threads
#define NITER 5         // contraction ~0.015: iter-5 error ~1e-9 << bf16 noise
#define KPAD 136        // lcb row stride in bf16 units

typedef __attribute__((ext_vector_type(8))) short short8;
typedef __attribute__((ext_vector_type(4))) short short4v;
typedef __attribute__((ext_vector_type(4))) float f32x4;

// RNE float -> bf16
static __device__ __forceinline__ short f2bf(float f) {
    unsigned u = __float_as_uint(f);
    return (short)((u + 0x7FFFu + ((u >> 16) & 1u)) >> 16);
}

// 8 waves x 512 threads. Wave w owns output rows [16w, 16w+16).
// MFMA 16x16x32 fragment roles (layout verified rounds 3-4):
//   A: row = 16w + (l&15), k = 32kt + 8*(l>>4) + i
//   B: col = l&15,         k = 32kt + 8*(l>>4) + i
//   D: col = l&15,         row = 16w + 4*(l>>4) + r
__global__ __launch_bounds__(512, 2) void vvl_main(const float* __restrict__ action,
                                                   const float* __restrict__ state,
                                                   const float2* __restrict__ K,
                                                   const float2* __restrict__ Lp,
                                                   float* __restrict__ out) {
    __shared__ float ev[COLS][128];
    __shared__ __align__(16) short lcb[2][2][COLS][KPAD];   // [buf][part][col][k]
    __shared__ float lossred[COLS];

    const int tid = threadIdx.x;
    const int w  = tid >> 6;         // wave 0..7
    const int l  = tid & 63;
    const int cc = l & 15;           // batch column within tile
    const int g  = l >> 4;           // lane group 0..3
    const int b0 = blockIdx.x * COLS;

    // --- build this wave's K A-fragments straight from global (bf16 RNE) ---
    short8 AKr[4], AKi[4];
    {
        const int arow = 16 * w + (l & 15);
        const bool rok = arow < N_BUS;
        const float2* Krow = K + (size_t)(rok ? arow : 0) * N_BUS;
        #pragma unroll
        for (int kt = 0; kt < 4; ++kt) {
            const int kb = 32 * kt + 8 * g;
            #pragma unroll
            for (int i = 0; i < 8; ++i) {
                int k = kb + i;
                float2 e = Krow[k < N_BUS ? k : 0];   // clamped, predicated below
                bool ok = rok && (k < N_BUS);
                AKr[kt][i] = f2bf(ok ? e.x : 0.0f);
                AKi[kt][i] = f2bf(ok ? e.y : 0.0f);
            }
        }
    }

    // zero ev + loss accumulators
    for (int i = tid; i < COLS * 128; i += 512) (&ev[0][0])[i] = 0.0f;
    if (tid < COLS) lossred[tid] = 0.0f;
    __syncthreads();

    // --- EV power + scatter-add to buses: 32 threads per column ---
    {
        int col = tid >> 5, j = tid & 31;
        const float* act_row = action + (size_t)(b0 + col) * NUM_CS;
        const float* st_row  = state  + (size_t)(b0 + col) * STATE_DIM;
        for (int cs = j; cs < NUM_CS; cs += 32) {
            float a    = act_row[cs];
            float cap  = st_row[EV_START + 3 * cs];
            float busf = st_row[EV_START + 2 + 3 * cs];
            float conn = (cap > 0.0f) ? 1.0f : 0.0f;
            float mch  = fminf(22.0f,  conn * (70.0f - cap) * 4.0f);  // /0.25 == *4
            float mds  = fmaxf(-22.0f, conn * (15.0f - cap) * 4.0f);
            float pw   = fmaxf(fminf(a * 22.17f, mch), mds);
            int bi = (int)busf;
            bi = bi < 0 ? 0 : (bi > N_BUS - 1 ? N_BUS - 1 : bi);
            atomicAdd(&ev[col][bi], pw);
        }
    }
    __syncthreads();

    // --- per-lane state: 4 rows (one M-tile) of column cc ---
    const float* st_row = state + (size_t)(b0 + cc) * STATE_DIM;
    float Sr[4], Si[4], lmr[4], lmi[4], vr[4], vi[4];
    #pragma unroll
    for (int r = 0; r < 4; ++r) {
        int row = 16 * w + 4 * g + r;
        if (row < N_BUS) {
            Sr[r] = (st_row[4 + row] + ev[cc][row]) * 1e-3f;
            Si[r] = st_row[4 + N_BUS + row] * 1e-3f;
            float2 lp = Lp[row];
            lmr[r] = lp.x; lmi[r] = lp.y;
        } else {  // pad row 127: S=0 -> Lc=0; A col 127 is zero anyway
            Sr[r] = 0.0f; Si[r] = 0.0f; lmr[r] = 1.0f; lmi[r] = 0.0f;
        }
        vr[r] = 1.0f; vi[r] = 0.0f;
    }

    // --- fixed-point loop: v = K @ conj(S/v) + L on matrix cores ---
    for (int it = 0; it < NITER; ++it) {
        const int buf = it & 1;
        // Lc = conj(S)*v/|v|^2 -> bf16, write rows this lane owns
        short4v pr, pi;
        #pragma unroll
        for (int r = 0; r < 4; ++r) {
            float d   = vr[r] * vr[r] + vi[r] * vi[r];
            float inv = __builtin_amdgcn_rcpf(d);
            pr[r] = f2bf((Sr[r] * vr[r] + Si[r] * vi[r]) * inv);
            pi[r] = f2bf((Sr[r] * vi[r] - Si[r] * vr[r]) * inv);
        }
        const int k0 = 16 * w + 4 * g;
        *(short4v*)&lcb[buf][0][cc][k0] = pr;
        *(short4v*)&lcb[buf][1][cc][k0] = pi;
        __syncthreads();   // single barrier/iter; WAR safe via double buffer

        short8 Br[4], Bi8[4];
        #pragma unroll
        for (int kt = 0; kt < 4; ++kt) {
            Br[kt]  = *(const short8*)&lcb[buf][0][cc][32 * kt + 8 * g];
            Bi8[kt] = *(const short8*)&lcb[buf][1][cc][32 * kt + 8 * g];
        }

        // Cre = Kr@Lr + Ki@(-Li) ; Cim = Kr@Li + Ki@Lr   (fp32 accum)
        f32x4 are = {0.f, 0.f, 0.f, 0.f}, aim = {0.f, 0.f, 0.f, 0.f};
        #pragma unroll
        for (int kt = 0; kt < 4; ++kt) {
            short8 Bin;
            #pragma unroll
            for (int i = 0; i < 8; ++i) Bin[i] = Bi8[kt][i] ^ (short)0x8000;
            are = __builtin_amdgcn_mfma_f32_16x16x32_bf16(AKr[kt], Br[kt],  are, 0, 0, 0);
            are = __builtin_amdgcn_mfma_f32_16x16x32_bf16(AKi[kt], Bin,     are, 0, 0, 0);
            aim = __builtin_amdgcn_mfma_f32_16x16x32_bf16(AKr[kt], Bi8[kt], aim, 0, 0, 0);
            aim = __builtin_amdgcn_mfma_f32_16x16x32_bf16(AKi[kt], Br[kt],  aim, 0, 0, 0);
        }
        #pragma unroll
        for (int r = 0; r < 4; ++r) {
            vr[r] = are[r] + lmr[r];
            vi[r] = aim[r] + lmi[r];
        }
    }

    // --- loss = 1000 * sum_n min(0, 0.05 - |1 - |v||) per column ---
    float ls = 0.0f;
    #pragma unroll
    for (int r = 0; r < 4; ++r) {
        int row = 16 * w + 4 * g + r;
        if (row < N_BUS) {
            float na = sqrtf(vr[r] * vr[r] + vi[r] * vi[r]);
            ls += fminf(0.0f, 0.05f - fabsf(1.0f - na));
        }
    }
    // reduce over the 4 lane-groups sharing column cc within this wave
    ls += __shfl_xor(ls, 16);
    ls += __shfl_xor(ls, 32);
    if (g == 0) atomicAdd(&lossred[cc], ls);   // 8 waves -> block total
    __syncthreads();
    if (tid < COLS) out[b0 + tid] = 1000.0f * lossred[tid];
}

extern "C" void kernel_launch(void* const* d_in, const int* in_sizes, int n_in,
                              void* d_out, int out_size, void* d_ws, size_t ws_size,
                              hipStream_t stream) {
    const float*  action = (const float*)d_in[0];
    const float*  state  = (const float*)d_in[1];
    const float2* K      = (const float2*)d_in[2];
    const float2* Lp     = (const float2*)d_in[3];
    float* out = (float*)d_out;

    vvl_main<<<BATCH / COLS, 512, 0, stream>>>(action, state, K, Lp, out);
}

// Round 6
// 17.701 us; speedup vs baseline: 1.7812x; 1.0398x over previous
//
#include <hip/hip_runtime.h>
#include <math.h>

#define N_BUS 127
#define BATCH 4096
#define NUM_CS 200
#define STATE_DIM 858   // 4 + 2*127 + 3*200
#define EV_START 258    // 4 + 2*127
#define COLS 16         // batch columns per block -> 256 blocks of 512 threads
#define NITER 5         // contraction ~0.015: iter-5 error ~1e-9 << bf16 noise
#define KPAD 136        // lcb row stride in bf16 units
#define SQS  258        // staged p/q stride (floats): 8B-aligned, bank-spread

typedef __attribute__((ext_vector_type(8))) short short8;
typedef __attribute__((ext_vector_type(4))) short short4v;
typedef __attribute__((ext_vector_type(4))) float f32x4;

// RNE float -> bf16
static __device__ __forceinline__ short f2bf(float f) {
    unsigned u = __float_as_uint(f);
    return (short)((u + 0x7FFFu + ((u >> 16) & 1u)) >> 16);
}

// 8 waves x 512 threads. Wave w owns output rows [16w, 16w+16).
// MFMA 16x16x32 fragment roles (layout verified rounds 3-5):
//   A: row = 16w + (l&15), k = 32kt + 8*(l>>4) + i
//   B: col = l&15,         k = 32kt + 8*(l>>4) + i
//   D: col = l&15,         row = 16w + 4*(l>>4) + r
__global__ __launch_bounds__(512, 4) void vvl_main(const float* __restrict__ action,
                                                   const float* __restrict__ state,
                                                   const float2* __restrict__ K,
                                                   const float2* __restrict__ Lp,
                                                   float* __restrict__ out) {
    // sq[col][0..127) = p rows (EV added in), sq[col][127..254) = q rows
    __shared__ float sq[COLS][SQS];
    __shared__ __align__(16) short lcb[2][2][COLS][KPAD];   // [buf][part][col][k]
    __shared__ float lossred[COLS];

    const int tid = threadIdx.x;
    const int w  = tid >> 6;         // wave 0..7
    const int l  = tid & 63;
    const int cc = l & 15;           // batch column within tile
    const int g  = l >> 4;           // lane group 0..3
    const int b0 = blockIdx.x * COLS;

    // --- build this wave's K A-fragments straight from global (bf16 RNE) ---
    short8 AKr[4], AKi[4];
    {
        const int arow = 16 * w + (l & 15);
        const bool rok = arow < N_BUS;
        const float2* Krow = K + (size_t)(rok ? arow : 0) * N_BUS;
        #pragma unroll
        for (int kt = 0; kt < 4; ++kt) {
            const int kb = 32 * kt + 8 * g;
            #pragma unroll
            for (int i = 0; i < 8; ++i) {
                int k = kb + i;
                float2 e = Krow[k < N_BUS ? k : 0];
                bool ok = rok && (k < N_BUS);
                AKr[kt][i] = f2bf(ok ? e.x : 0.0f);
                AKi[kt][i] = f2bf(ok ? e.y : 0.0f);
            }
        }
    }

    // --- stage p/q (floats 4..258 of each state row) into LDS, coalesced ---
    {
        int col = tid >> 5, j = tid & 31;
        const float2* st2 = (const float2*)(state + (size_t)(b0 + col) * STATE_DIM + 4);
        #pragma unroll
        for (int jj = 0; jj < 4; ++jj) {
            int idx = j + 32 * jj;
            if (idx < 127) *(float2*)&sq[col][2 * idx] = st2[idx];
        }
    }
    if (tid < COLS) lossred[tid] = 0.0f;
    __syncthreads();

    // --- EV power + scatter-add into staged p: 32 threads per column ---
    {
        int col = tid >> 5, j = tid & 31;
        const float* act_row = action + (size_t)(b0 + col) * NUM_CS;
        const float* st_row  = state  + (size_t)(b0 + col) * STATE_DIM;
        for (int cs = j; cs < NUM_CS; cs += 32) {
            float a    = act_row[cs];
            float cap  = st_row[EV_START + 3 * cs];
            float busf = st_row[EV_START + 2 + 3 * cs];
            float conn = (cap > 0.0f) ? 1.0f : 0.0f;
            float mch  = fminf(22.0f,  conn * (70.0f - cap) * 4.0f);  // /0.25 == *4
            float mds  = fmaxf(-22.0f, conn * (15.0f - cap) * 4.0f);
            float pw   = fmaxf(fminf(a * 22.17f, mch), mds);
            int bi = (int)busf;
            bi = bi < 0 ? 0 : (bi > N_BUS - 1 ? N_BUS - 1 : bi);
            atomicAdd(&sq[col][bi], pw);
        }
    }
    __syncthreads();

    // --- per-lane state: 4 rows (one M-tile) of column cc, from LDS ---
    float Sr[4], Si[4], lmr[4], lmi[4], vr[4], vi[4];
    #pragma unroll
    for (int r = 0; r < 4; ++r) {
        int row = 16 * w + 4 * g + r;
        if (row < N_BUS) {
            Sr[r] = sq[cc][row] * 1e-3f;
            Si[r] = sq[cc][127 + row] * 1e-3f;
            float2 lp = Lp[row];
            lmr[r] = lp.x; lmi[r] = lp.y;
        } else {  // pad row 127: S=0 -> Lc=0; A col 127 is zero anyway
            Sr[r] = 0.0f; Si[r] = 0.0f; lmr[r] = 1.0f; lmi[r] = 0.0f;
        }
        vr[r] = 1.0f; vi[r] = 0.0f;
    }

    // --- fixed-point loop: v = K @ conj(S/v) + L on matrix cores ---
    for (int it = 0; it < NITER; ++it) {
        const int buf = it & 1;
        // Lc = conj(S)*v/|v|^2 -> bf16, write rows this lane owns
        short4v pr, pi;
        #pragma unroll
        for (int r = 0; r < 4; ++r) {
            float d   = vr[r] * vr[r] + vi[r] * vi[r];
            float inv = __builtin_amdgcn_rcpf(d);
            pr[r] = f2bf((Sr[r] * vr[r] + Si[r] * vi[r]) * inv);
            pi[r] = f2bf((Sr[r] * vi[r] - Si[r] * vr[r]) * inv);
        }
        const int k0 = 16 * w + 4 * g;
        *(short4v*)&lcb[buf][0][cc][k0] = pr;
        *(short4v*)&lcb[buf][1][cc][k0] = pi;
        __syncthreads();   // single barrier/iter; WAR safe via double buffer

        // Cre = Kr@Lr + Ki@(-Li) ; Cim = Kr@Li + Ki@Lr   (fp32 accum)
        f32x4 are = {0.f, 0.f, 0.f, 0.f}, aim = {0.f, 0.f, 0.f, 0.f};
        #pragma unroll
        for (int kt = 0; kt < 4; ++kt) {
            short8 Br  = *(const short8*)&lcb[buf][0][cc][32 * kt + 8 * g];
            short8 Bi8 = *(const short8*)&lcb[buf][1][cc][32 * kt + 8 * g];
            aim = __builtin_amdgcn_mfma_f32_16x16x32_bf16(AKr[kt], Bi8, aim, 0, 0, 0);
            aim = __builtin_amdgcn_mfma_f32_16x16x32_bf16(AKi[kt], Br,  aim, 0, 0, 0);
            are = __builtin_amdgcn_mfma_f32_16x16x32_bf16(AKr[kt], Br,  are, 0, 0, 0);
            #pragma unroll
            for (int i = 0; i < 8; ++i) Bi8[i] = Bi8[i] ^ (short)0x8000;   // -Li
            are = __builtin_amdgcn_mfma_f32_16x16x32_bf16(AKi[kt], Bi8, are, 0, 0, 0);
        }
        #pragma unroll
        for (int r = 0; r < 4; ++r) {
            vr[r] = are[r] + lmr[r];
            vi[r] = aim[r] + lmi[r];
        }
    }

    // --- loss = 1000 * sum_n min(0, 0.05 - |1 - |v||) per column ---
    float ls = 0.0f;
    #pragma unroll
    for (int r = 0; r < 4; ++r) {
        int row = 16 * w + 4 * g + r;
        if (row < N_BUS) {
            float na = sqrtf(vr[r] * vr[r] + vi[r] * vi[r]);
            ls += fminf(0.0f, 0.05f - fabsf(1.0f - na));
        }
    }
    // reduce over the 4 lane-groups sharing column cc within this wave
    ls += __shfl_xor(ls, 16);
    ls += __shfl_xor(ls, 32);
    if (g == 0) atomicAdd(&lossred[cc], ls);   // 8 waves -> block total
    __syncthreads();
    if (tid < COLS) out[b0 + tid] = 1000.0f * lossred[tid];
}

extern "C" void kernel_launch(void* const* d_in, const int* in_sizes, int n_in,
                              void* d_out, int out_size, void* d_ws, size_t ws_size,
                              hipStream_t stream) {
    const float*  action = (const float*)d_in[0];
    const float*  state  = (const float*)d_in[1];
    const float2* K      = (const float2*)d_in[2];
    const float2* Lp     = (const float2*)d_in[3];
    float* out = (float*)d_out;

    vvl_main<<<BATCH / COLS, 512, 0, stream>>>(action, state, K, Lp, out);
}

// Round 7
// 17.042 us; speedup vs baseline: 1.8501x; 1.0387x over previous
//
#include <hip/hip_runtime.h>
#include <math.h>

#define N_BUS 127
#define BATCH 4096
#define NUM_CS 200
#define STATE_DIM 858   // 4 + 2*127 + 3*200
#define EV_START 258    // 4 + 2*127
#define COLS 16         // batch columns per block -> 256 blocks of 512 threads
#define NITER 5         // contraction ~0.015: iter-5 error ~1e-9 << bf16 noise

typedef __attribute__((ext_vector_type(8))) short short8;
typedef __attribute__((ext_vector_type(4))) short short4v;
typedef __attribute__((ext_vector_type(4))) float f32x4;

// RNE float -> bf16
static __device__ __forceinline__ short f2bf(float f) {
    unsigned u = __float_as_uint(f);
    return (short)((u + 0x7FFFu + ((u >> 16) & 1u)) >> 16);
}

// 8 waves x 512 threads. Wave w owns output rows [16w, 16w+16).
// MFMA 16x16x32 fragment roles (layout verified rounds 3-6):
//   A: row = 16w + (l&15), k = 32kt + 8*(l>>4) + i
//   B: col = l&15,         k = 32kt + 8*(l>>4) + i
//   D: col = l&15,         row = 16w + 4*(l>>4) + r
__global__ __launch_bounds__(512, 4) void vvl_main(const float* __restrict__ action,
                                                   const float* __restrict__ state,
                                                   const float2* __restrict__ K,
                                                   const float2* __restrict__ Lp,
                                                   float* __restrict__ out) {
    // sq[col][0..127) = p (EV added in), [127..254) = q
    __shared__ float sq[COLS][258];
    // B fragments, lane-linear: B8[buf][part][kt][g][cc] = short8 for
    // (col=cc, k=32kt+8g..+7). Reader byte addr = const + 16*lane -> conflict-free.
    __shared__ __align__(16) short B8[2][2][4][4][COLS][8];
    __shared__ float lossred[COLS];

    const int tid = threadIdx.x;
    const int w  = tid >> 6;         // wave 0..7
    const int l  = tid & 63;
    const int cc = l & 15;           // batch column within tile
    const int g  = l >> 4;           // lane group 0..3
    const int b0 = blockIdx.x * COLS;
    const int col = tid >> 5;        // prologue column mapping (32 thr/col)
    const int j   = tid & 31;

    const float*  st_row_c = state + (size_t)(b0 + col) * STATE_DIM;
    const float2* st2      = (const float2*)(st_row_c + 4);
    const float*  act_row  = action + (size_t)(b0 + col) * NUM_CS;

    // ---- batch 1: p/q loads (consumed first; in-order VMEM return) ----
    float2 pqv[4];
    #pragma unroll
    for (int jj = 0; jj < 4; ++jj) {
        int idx = j + 32 * jj; idx = idx < 127 ? idx : 126;
        pqv[jj] = st2[idx];
    }
    // ---- batch 2: EV loads (21 independent scalars, uniform trip count) ----
    float av[7], capv[7], busv[7];
    #pragma unroll
    for (int kk = 0; kk < 7; ++kk) {
        int cs = j + 32 * kk; int csc = cs < NUM_CS ? cs : NUM_CS - 1;
        av[kk]   = act_row[csc];
        capv[kk] = st_row_c[EV_START + 3 * csc];
        busv[kk] = st_row_c[EV_START + 2 + 3 * csc];
    }
    // ---- batch 3: K first half (kt 0,1) ----
    const int arow = 16 * w + (l & 15);
    const bool rok = arow < N_BUS;
    const float2* Krow = K + (size_t)(rok ? arow : 0) * N_BUS;
    float2 k1[16];
    #pragma unroll
    for (int kt = 0; kt < 2; ++kt)
        #pragma unroll
        for (int i = 0; i < 8; ++i) {
            int k = 32 * kt + 8 * g + i;
            k1[kt * 8 + i] = Krow[k < N_BUS ? k : 0];
        }

    if (tid < COLS) lossred[tid] = 0.0f;
    // store pq (s_waitcnt covers batch 1 only; EV/K still in flight)
    #pragma unroll
    for (int jj = 0; jj < 4; ++jj) {
        int idx = j + 32 * jj;
        if (idx < 127) *(float2*)&sq[col][2 * idx] = pqv[jj];
    }
    __syncthreads();

    // ---- EV power + scatter-add into staged p ----
    #pragma unroll
    for (int kk = 0; kk < 7; ++kk) {
        int cs = j + 32 * kk;
        float cap  = capv[kk];
        float conn = (cap > 0.0f) ? 1.0f : 0.0f;
        float mch  = fminf(22.0f,  conn * (70.0f - cap) * 4.0f);  // /0.25 == *4
        float mds  = fmaxf(-22.0f, conn * (15.0f - cap) * 4.0f);
        float pw   = fmaxf(fminf(av[kk] * 22.17f, mch), mds);
        int bi = (int)busv[kk];
        bi = bi < 0 ? 0 : (bi > N_BUS - 1 ? N_BUS - 1 : bi);
        if (cs < NUM_CS) atomicAdd(&sq[col][bi], pw);
    }

    // ---- batch 4: K second half (latency hides under K1 convert + S-build) ----
    float2 k2[16];
    #pragma unroll
    for (int kt = 2; kt < 4; ++kt)
        #pragma unroll
        for (int i = 0; i < 8; ++i) {
            int k = 32 * kt + 8 * g + i;
            k2[(kt - 2) * 8 + i] = Krow[k < N_BUS ? k : 0];
        }

    // convert K1 -> bf16 A-fragments while K2 is in flight
    short8 AKr[4], AKi[4];
    #pragma unroll
    for (int kt = 0; kt < 2; ++kt)
        #pragma unroll
        for (int i = 0; i < 8; ++i) {
            int k = 32 * kt + 8 * g + i;
            bool ok = rok && (k < N_BUS);
            float2 e = k1[kt * 8 + i];
            AKr[kt][i] = f2bf(ok ? e.x : 0.0f);
            AKi[kt][i] = f2bf(ok ? e.y : 0.0f);
        }

    __syncthreads();   // sq final (atomics done)

    // ---- per-lane S/v state from LDS ----
    float Sr[4], Si[4], lmr[4], lmi[4], vr[4], vi[4];
    #pragma unroll
    for (int r = 0; r < 4; ++r) {
        int row = 16 * w + 4 * g + r;
        if (row < N_BUS) {
            Sr[r] = sq[cc][row] * 1e-3f;
            Si[r] = sq[cc][127 + row] * 1e-3f;
            float2 lp = Lp[row];
            lmr[r] = lp.x; lmi[r] = lp.y;
        } else {  // pad row 127: S=0 -> Lc=0; A col 127 is zero anyway
            Sr[r] = 0.0f; Si[r] = 0.0f; lmr[r] = 1.0f; lmi[r] = 0.0f;
        }
        vr[r] = 1.0f; vi[r] = 0.0f;
    }

    // convert K2
    #pragma unroll
    for (int kt = 2; kt < 4; ++kt)
        #pragma unroll
        for (int i = 0; i < 8; ++i) {
            int k = 32 * kt + 8 * g + i;
            bool ok = rok && (k < N_BUS);
            float2 e = k2[(kt - 2) * 8 + i];
            AKr[kt][i] = f2bf(ok ? e.x : 0.0f);
            AKi[kt][i] = f2bf(ok ? e.y : 0.0f);
        }

    // writer-side B8 constants: this lane owns k = k0..k0+3 of column cc
    const int k0  = 16 * w + 4 * g;
    const int ktw = k0 >> 5;
    const int gi  = (k0 >> 3) & 3;
    const int i0  = k0 & 7;          // 0 or 4

    // ---- fixed-point loop: v = K @ conj(S/v) + L on matrix cores ----
    for (int it = 0; it < NITER; ++it) {
        const int buf = it & 1;
        short4v pr, pi;
        #pragma unroll
        for (int r = 0; r < 4; ++r) {
            float d   = vr[r] * vr[r] + vi[r] * vi[r];
            float inv = __builtin_amdgcn_rcpf(d);
            pr[r] = f2bf((Sr[r] * vr[r] + Si[r] * vi[r]) * inv);
            pi[r] = f2bf((Sr[r] * vi[r] - Si[r] * vr[r]) * inv);
        }
        *(short4v*)&B8[buf][0][ktw][gi][cc][i0] = pr;
        *(short4v*)&B8[buf][1][ktw][gi][cc][i0] = pi;
        __syncthreads();   // single barrier/iter; WAR safe via double buffer

        // Cre = Kr@Lr + Ki@(-Li) ; Cim = Kr@Li + Ki@Lr   (fp32 accum)
        f32x4 are = {0.f, 0.f, 0.f, 0.f}, aim = {0.f, 0.f, 0.f, 0.f};
        #pragma unroll
        for (int kt = 0; kt < 4; ++kt) {
            short8 Br  = *(const short8*)&B8[buf][0][kt][g][cc][0];
            short8 Bi8 = *(const short8*)&B8[buf][1][kt][g][cc][0];
            aim = __builtin_amdgcn_mfma_f32_16x16x32_bf16(AKr[kt], Bi8, aim, 0, 0, 0);
            aim = __builtin_amdgcn_mfma_f32_16x16x32_bf16(AKi[kt], Br,  aim, 0, 0, 0);
            are = __builtin_amdgcn_mfma_f32_16x16x32_bf16(AKr[kt], Br,  are, 0, 0, 0);
            #pragma unroll
            for (int i = 0; i < 8; ++i) Bi8[i] = Bi8[i] ^ (short)0x8000;   // -Li
            are = __builtin_amdgcn_mfma_f32_16x16x32_bf16(AKi[kt], Bi8, are, 0, 0, 0);
        }
        #pragma unroll
        for (int r = 0; r < 4; ++r) {
            vr[r] = are[r] + lmr[r];
            vi[r] = aim[r] + lmi[r];
        }
    }

    // ---- loss = 1000 * sum_n min(0, 0.05 - |1 - |v||) per column ----
    float ls = 0.0f;
    #pragma unroll
    for (int r = 0; r < 4; ++r) {
        int row = 16 * w + 4 * g + r;
        if (row < N_BUS) {
            float na = sqrtf(vr[r] * vr[r] + vi[r] * vi[r]);
            ls += fminf(0.0f, 0.05f - fabsf(1.0f - na));
        }
    }
    // reduce over the 4 lane-groups sharing column cc within this wave
    ls += __shfl_xor(ls, 16);
    ls += __shfl_xor(ls, 32);
    if (g == 0) atomicAdd(&lossred[cc], ls);   // 8 waves -> block total
    __syncthreads();
    if (tid < COLS) out[b0 + tid] = 1000.0f * lossred[tid];
}

extern "C" void kernel_launch(void* const* d_in, const int* in_sizes, int n_in,
                              void* d_out, int out_size, void* d_ws, size_t ws_size,
                              hipStream_t stream) {
    const float*  action = (const float*)d_in[0];
    const float*  state  = (const float*)d_in[1];
    const float2* K      = (const float2*)d_in[2];
    const float2* Lp     = (const float2*)d_in[3];
    float* out = (float*)d_out;

    vvl_main<<<BATCH / COLS, 512, 0, stream>>>(action, state, K, Lp, out);
}